// Round 5
// baseline (126.396 us; speedup 1.0000x reference)
//
#include <hip/hip_runtime.h>
#include <cstdint>

typedef float v4f __attribute__((ext_vector_type(4)));
typedef float v2f __attribute__((ext_vector_type(2)));

// fast reciprocal: v_rcp_f32 + 1 Newton-Raphson step (~1 ulp)
__device__ __forceinline__ float frcp(float x) {
    float r = __builtin_amdgcn_rcpf(x);
    return r * (2.0f - x * r);
}
// fast rsqrt: v_rsq_f32 + 1 Newton-Raphson step
__device__ __forceinline__ float frsq(float x) {
    float r = __builtin_amdgcn_rsqf(x);
    return r * (1.5f - 0.5f * x * r * r);
}

struct POut { float u, v, zc, o00, o01, o10, o11; };

// Wave-decoupled version: each wave owns 256 consecutive points and stages its
// own points/scales slice into its private LDS region — NO __syncthreads().
// DS ops are in-order per wave, so ds_write -> ds_read within one wave needs
// no barrier (wave_barrier pins compiler scheduling). All 10 global loads are
// issued before the first ds_write, so quat latency hides under staging.
// quats/uv/z/cov accesses are lane-contiguous (fully coalesced, direct).
// LDS compute reads are word-stride 3: gcd(3,32)=1 -> bank-conflict-free.
__global__ __launch_bounds__(256) void gs_project_kernel(
    const float* __restrict__ points,   // N*3
    const float* __restrict__ quats,    // N*4
    const float* __restrict__ scales,   // N*3
    const float* __restrict__ E,        // 16 (4x4 row-major extrinsic)
    const float* __restrict__ K,        // 12 (3x4 row-major intrinsic)
    float* __restrict__ out,            // [uv: 2N][z: N][cov: 4N]
    int n)
{
    const int tid  = threadIdx.x;
    const int lane = tid & 63;
    const int wv   = tid >> 6;
    const long long blockBase = (long long)blockIdx.x * 1024;

    __shared__ float lds_p[3072];   // 4 waves x 256 points x 3
    __shared__ float lds_s[3072];

    // Wave-uniform broadcast loads (stay in SGPRs).
    const float e00=E[0],  e01=E[1],  e02=E[2],  e03=E[3];
    const float e10=E[4],  e11=E[5],  e12=E[6],  e13=E[7];
    const float e20=E[8],  e21=E[9],  e22=E[10], e23=E[11];
    const float e30=E[12], e31=E[13], e32=E[14], e33=E[15];
    const float k00=K[0],  k01=K[1],  k02=K[2],  k03=K[3];
    const float k10=K[4],  k11=K[5],  k12=K[6],  k13=K[7];
    const float k20=K[8],  k21=K[9],  k22=K[10], k23=K[11];

    auto project = [&](float px, float py, float pz,
                       float qw, float qx, float qy, float qz_,
                       float sx, float sy, float sz) -> POut
    {
        const float qi = frsq(qw*qw + qx*qx + qy*qy + qz_*qz_);
        const float w = qw*qi, x = qx*qi, y = qy*qi, z = qz_*qi;

        const float r00 = 1.f - 2.f*(y*y + z*z);
        const float r01 = 2.f*(x*y - w*z);
        const float r02 = 2.f*(x*z + w*y);
        const float r10 = 2.f*(x*y + w*z);
        const float r11 = 1.f - 2.f*(x*x + z*z);
        const float r12 = 2.f*(y*z - w*x);
        const float r20 = 2.f*(x*z - w*y);
        const float r21 = 2.f*(y*z + w*x);
        const float r22 = 1.f - 2.f*(x*x + y*y);

        const float m00=r00*sx, m01=r01*sy, m02=r02*sz;
        const float m10=r10*sx, m11=r11*sy, m12=r12*sz;
        const float m20=r20*sx, m21=r21*sy, m22=r22*sz;

        const float c00 = m00*m00 + m01*m01 + m02*m02;
        const float c01 = m00*m10 + m01*m11 + m02*m12;
        const float c02 = m00*m20 + m01*m21 + m02*m22;
        const float c11 = m10*m10 + m11*m11 + m12*m12;
        const float c12 = m10*m20 + m11*m21 + m12*m22;
        const float c22 = m20*m20 + m21*m21 + m22*m22;

        const float camx = e00*px + e01*py + e02*pz + e03;
        const float camy = e10*px + e11*py + e12*pz + e13;
        const float camz = e20*px + e21*py + e22*pz + e23;
        const float camw = e30*px + e31*py + e32*pz + e33;
        const float iw = frcp(camw);
        const float cx = camx*iw, cy = camy*iw, cz = camz*iw;

        const float p0 = k00*cx + k01*cy + k02*cz + k03;
        const float p1 = k10*cx + k11*cy + k12*cz + k13;
        const float p2 = k20*cx + k21*cy + k22*cz + k23;
        const float ip2 = frcp(p2);

        const float fx = k00, fy = k11;
        const float icz = frcp(cz);
        const float j00 = fx*icz;
        const float j02 = -fx*cx*icz*icz;
        const float j11 = fy*icz;
        const float j12 = -fy*cy*icz*icz;

        // T = J @ E[:3,:3]
        const float t00 = j00*e00 + j02*e20;
        const float t01 = j00*e01 + j02*e21;
        const float t02 = j00*e02 + j02*e22;
        const float t10 = j11*e10 + j12*e20;
        const float t11 = j11*e11 + j12*e21;
        const float t12 = j11*e12 + j12*e22;

        const float a00 = t00*c00 + t01*c01 + t02*c02;
        const float a01 = t00*c01 + t01*c11 + t02*c12;
        const float a02 = t00*c02 + t01*c12 + t02*c22;
        const float a10 = t10*c00 + t11*c01 + t12*c02;
        const float a11 = t10*c01 + t11*c11 + t12*c12;
        const float a12 = t10*c02 + t11*c12 + t12*c22;

        POut o;
        o.u  = p0*ip2;
        o.v  = p1*ip2;
        o.zc = camz;                     // z_component is pre-divide cam[:,2]
        o.o00 = a00*t00 + a01*t01 + a02*t02;
        o.o01 = a00*t10 + a01*t11 + a02*t12;
        o.o10 = a10*t00 + a11*t01 + a12*t02;
        o.o11 = a10*t10 + a11*t11 + a12*t12;
        return o;
    };

    if (blockBase + 1024 <= n) {
        // ---- fast path: this wave owns points [waveBase, waveBase+256) ----
        const long long waveBase = blockBase + 256*wv;
        const size_t pvBase = (size_t)blockIdx.x * 768 + 192*wv; // v4f idx, points/scales

        const v4f* gp4 = (const v4f*)points;
        const v4f* gs4 = (const v4f*)scales;
        const v4f* gq4 = (const v4f*)quats;

        // Issue ALL global loads up front: 6 staging + 4 quat (160 B/lane in flight).
        const v4f sp0 = gp4[pvBase + lane];
        const v4f sp1 = gp4[pvBase + lane + 64];
        const v4f sp2 = gp4[pvBase + lane + 128];
        const v4f ss0 = gs4[pvBase + lane];
        const v4f ss1 = gs4[pvBase + lane + 64];
        const v4f ss2 = gs4[pvBase + lane + 128];
        const v4f q0 = gq4[waveBase + lane];
        const v4f q1 = gq4[waveBase + 64 + lane];
        const v4f q2 = gq4[waveBase + 128 + lane];
        const v4f q3 = gq4[waveBase + 192 + lane];

        // Wave-private LDS slice; ds_writes wait only on sp*/ss* (vmcnt(4):
        // the four quat loads stay outstanding).
        v4f* lp4 = (v4f*)lds_p + 192*(size_t)wv;
        v4f* ls4 = (v4f*)lds_s + 192*(size_t)wv;
        lp4[lane]      = sp0;  ls4[lane]      = ss0;
        lp4[lane + 64] = sp1;  ls4[lane + 64] = ss1;
        lp4[lane +128] = sp2;  ls4[lane +128] = ss2;
        __builtin_amdgcn_wave_barrier();   // pin sched: DS pipe is in-order per wave

        const float* wp = lds_p + 768*(size_t)wv;
        const float* ws = lds_s + 768*(size_t)wv;

        v2f* uvout = (v2f*)out;
        float* zout = out + 2*(size_t)n;
        v4f* cout = (v4f*)(out + 3*(size_t)n);

        auto doPoint = [&](int k, const v4f& q) {
            const long long p = waveBase + 64*k + lane;   // global point idx
            const int pl = 3*(64*k + lane);               // word idx in wave slice
            const float px = wp[pl+0], py = wp[pl+1], pz = wp[pl+2];
            const float sx = ws[pl+0], sy = ws[pl+1], sz = ws[pl+2];
            const POut r = project(px, py, pz, q.x, q.y, q.z, q.w, sx, sy, sz);
            uvout[p] = (v2f){r.u, r.v};                   // coalesced 8 B/lane
            zout[p]  = r.zc;                              // coalesced 4 B/lane
            cout[p]  = (v4f){r.o00, r.o01, r.o10, r.o11}; // coalesced 16 B/lane
        };
        doPoint(0, q0);
        doPoint(1, q1);
        doPoint(2, q2);
        doPoint(3, q3);
    } else {
        // ---- tail block: scalar per point ----
        for (long long i = blockBase + tid; i < n; i += 256) {
            const POut r = project(points[3*i+0], points[3*i+1], points[3*i+2],
                                   quats[4*i+0], quats[4*i+1], quats[4*i+2], quats[4*i+3],
                                   scales[3*i+0], scales[3*i+1], scales[3*i+2]);
            out[2*i+0] = r.u; out[2*i+1] = r.v;
            out[2*(size_t)n + i] = r.zc;
            float* cov_out = out + 3*(size_t)n + 4*i;
            cov_out[0] = r.o00; cov_out[1] = r.o01; cov_out[2] = r.o10; cov_out[3] = r.o11;
        }
    }
}

extern "C" void kernel_launch(void* const* d_in, const int* in_sizes, int n_in,
                              void* d_out, int out_size, void* d_ws, size_t ws_size,
                              hipStream_t stream) {
    const float* points = (const float*)d_in[0];
    const float* quats  = (const float*)d_in[1];
    const float* scales = (const float*)d_in[2];
    const float* E      = (const float*)d_in[3];
    const float* K      = (const float*)d_in[4];
    float* out = (float*)d_out;

    const int n = in_sizes[0] / 3;
    const int block = 256;                      // 4 waves, 1024 points/block
    const int grid = (n + 1023) / 1024;
    gs_project_kernel<<<grid, block, 0, stream>>>(points, quats, scales, E, K, out, n);
}